// Round 12
// baseline (421.404 us; speedup 1.0000x reference)
//
#include <hip/hip_runtime.h>
#include <hip/hip_fp16.h>
#include <math.h>

#define NN 50000
#define NE 800000
#define NLAYERS 8
#define NTILE (NN / 16)                     // 3125 16-node tiles
#define EPB (NE / 256)                      // 3125 edges per hist/part block
#define NBUCKB ((NN + 255) / 256)           // 196 buckets in use
#define BCAP 5120                           // max edges per bucket
#define CSRCAP 768                          // max edges per tile (sorted: 16*maxdeg)

typedef _Float16 f16x8 __attribute__((ext_vector_type(8)));
typedef float f32x4 __attribute__((ext_vector_type(4)));

// ---------------- CSR build: 4-pass radix partition (R8 gh orientation) ----------------

__global__ __launch_bounds__(256) void k_hist(const int* __restrict__ ei,
                                              int* __restrict__ gh) {
    __shared__ int h[256];
    h[threadIdx.x] = 0;
    __syncthreads();
    int base = blockIdx.x * EPB;
    for (int i = threadIdx.x; i < EPB; i += 256) {
        int d = __builtin_nontemporal_load(ei + NE + base + i);
        atomicAdd(&h[d >> 8], 1);
    }
    __syncthreads();
    gh[blockIdx.x * 256 + threadIdx.x] = h[threadIdx.x];
}

__global__ void k_scanhist(int* __restrict__ gh, int* __restrict__ bbase) {
    __shared__ int tot[256];
    int t = threadIdx.x;
    int run = 0;
    for (int blk = 0; blk < 256; blk++) {
        int v = gh[blk * 256 + t];
        gh[blk * 256 + t] = run;
        run += v;
    }
    tot[t] = run;
    __syncthreads();
    for (int off = 1; off < 256; off <<= 1) {
        int u = (t >= off) ? tot[t - off] : 0;
        __syncthreads();
        tot[t] += u;
        __syncthreads();
    }
    int ebase = tot[t] - run;
    for (int blk = 0; blk < 256; blk++) gh[blk * 256 + t] += ebase;
    bbase[t] = ebase;
    if (t == 255) bbase[256] = NE;
}

__global__ __launch_bounds__(256) void k_part(const int* __restrict__ ei,
                                              const int* __restrict__ gh,
                                              int2* __restrict__ part) {
    __shared__ int lcnt[256];
    int t = threadIdx.x;
    lcnt[t] = gh[blockIdx.x * 256 + t];
    __syncthreads();
    int base = blockIdx.x * EPB;
    for (int i = t; i < EPB; i += 256) {
        int s = __builtin_nontemporal_load(ei + base + i);
        int d = __builtin_nontemporal_load(ei + NE + base + i);
        int pos = atomicAdd(&lcnt[d >> 8], 1);
        int2 e; e.x = s; e.y = d;
        part[pos] = e;
    }
}

__global__ __launch_bounds__(256) void k_bsort(const int2* __restrict__ part,
                                               const int* __restrict__ bbase,
                                               int* __restrict__ csrs,
                                               int* __restrict__ offs,
                                               float* __restrict__ dinv,
                                               float* __restrict__ rdinv) {
    __shared__ int ssrc[BCAP];
    __shared__ unsigned char sdlo[BCAP];
    __shared__ int dcnt[256], dpos[256], scan[256];
    int b = blockIdx.x, t = threadIdx.x;
    int base0 = bbase[b], base1 = bbase[b + 1];
    int n = base1 - base0;
    if (n > BCAP) n = BCAP;
    dcnt[t] = 0;
    __syncthreads();
    for (int i = t; i < n; i += 256) {
        int2 e = part[base0 + i];
        ssrc[i] = e.x;
        int dlo = e.y & 255;
        sdlo[i] = (unsigned char)dlo;
        atomicAdd(&dcnt[dlo], 1);
    }
    __syncthreads();
    int cnt = dcnt[t];
    scan[t] = cnt;
    __syncthreads();
    for (int off = 1; off < 256; off <<= 1) {
        int u = (t >= off) ? scan[t - off] : 0;
        __syncthreads();
        scan[t] += u;
        __syncthreads();
    }
    int ebase = scan[t] - cnt;
    dpos[t] = ebase;
    __syncthreads();
    for (int i = t; i < n; i += 256) {
        int d = sdlo[i];
        int r = atomicAdd(&dpos[d], 1);
        csrs[base0 + r] = ssrc[i];
    }
    int gdst = b * 256 + t;
    if (gdst < NN) {
        offs[gdst] = base0 + ebase;
        float dd = (float)(cnt + 1);
        dinv[gdst] = rsqrtf(dd);
        rdinv[gdst] = sqrtf(dd);
    } else if (gdst == NN) {
        offs[NN] = NE;
    }
}

// ---------------- degree-rank permutation ----------------
// rank space: nodes sorted by degree -> uniform-degree tiles (gather loop trips
// uniform across the wave; clamped-waste drops from ~37% to ~6%).

__global__ __launch_bounds__(256) void k_deghist(const int* __restrict__ offs,
                                                 int* __restrict__ dh) {
    __shared__ int h[64];
    if (threadIdx.x < 64) h[threadIdx.x] = 0;
    __syncthreads();
    int i = blockIdx.x * 256 + threadIdx.x;
    if (i < NN) {
        int d = offs[i + 1] - offs[i];
        if (d > 63) d = 63;
        atomicAdd(&h[d], 1);
    }
    __syncthreads();
    if (threadIdx.x < 64) atomicAdd(&dh[threadIdx.x], h[threadIdx.x]);
}

// 1 block, 64 threads: exclusive scans of counts and count*deg
__global__ void k_degscan(const int* __restrict__ dh, int* __restrict__ dbase,
                          int* __restrict__ ebase, int* __restrict__ binpos) {
    __shared__ int sc[64], se[64];
    int t = threadIdx.x;
    int c = dh[t];
    sc[t] = c;
    se[t] = c * t;
    __syncthreads();
    for (int off = 1; off < 64; off <<= 1) {
        int u = (t >= off) ? sc[t - off] : 0;
        int v = (t >= off) ? se[t - off] : 0;
        __syncthreads();
        sc[t] += u; se[t] += v;
        __syncthreads();
    }
    dbase[t] = sc[t] - c;
    binpos[t] = sc[t] - c;
    ebase[t] = se[t] - c * t;
}

__global__ __launch_bounds__(256) void k_rank(const int* __restrict__ offs,
        int* __restrict__ binpos, const int* __restrict__ dbase,
        const int* __restrict__ ebase,
        const float* __restrict__ dinv, const float* __restrict__ rdinv,
        int* __restrict__ rank, int* __restrict__ iperm, int* __restrict__ offsp,
        float* __restrict__ dinvp, float* __restrict__ rdinvp) {
    int i = blockIdx.x * 256 + threadIdx.x;
    if (i >= NN) return;
    int d = offs[i + 1] - offs[i];
    if (d > 63) d = 63;
    int r = atomicAdd(&binpos[d], 1);
    rank[i] = r;
    iperm[r] = i;
    dinvp[r] = dinv[i];
    rdinvp[r] = rdinv[i];
    offsp[r] = ebase[d] + (r - dbase[d]) * d;
    if (i == 0) offsp[NN] = NE;
}

// csr -> rank space: slice of node i moves wholesale to offsp[rank[i]], srcs remapped
__global__ __launch_bounds__(256) void k_remap(const int* __restrict__ offs,
        const int* __restrict__ rank, const int* __restrict__ offsp,
        const int* __restrict__ csrs, int* __restrict__ csrs2) {
    int i = blockIdx.x * 256 + threadIdx.x;
    if (i >= NN) return;
    int b = offs[i], e = offs[i + 1];
    int ob = offsp[rank[i]];
    for (int k = b; k < e; k++)
        csrs2[ob + (k - b)] = rank[csrs[k]];
}

// ---------------- other setup ----------------
// MERGED row layout: row[r] = 128B = 64 halves (feats 0-63), RANK space.

__global__ void k_zrow(__half2* a, __half2* b) {
    int t = threadIdx.x;
    __half2 z = __floats2half2_rn(0.f, 0.f);
    if (t < 32) a[NN * 32 + t] = z;
    else b[NN * 32 + (t & 31)] = z;
}

// frag[fid][lane][j] = B[k = kt*32 + (lane>>4)*8 + j][n = nb*16 + (lane&15)]
__global__ void k_makefrag(const float* __restrict__ W0, const float* __restrict__ Ws,
                           const float* __restrict__ Wout, __half* __restrict__ frag) {
    int fid = blockIdx.x;
    int lane = threadIdx.x;
    int m = lane & 15, g = lane >> 4;
#pragma unroll
    for (int j = 0; j < 8; j++) {
        float v;
        if (fid < 16) {
            int kt = fid >> 2, nb = fid & 3;
            int k = kt * 32 + g * 8 + j, n = nb * 16 + m;
            v = W0[k * 64 + n];
        } else if (fid < 80) {
            int t = fid - 16;
            int l = t >> 3, kt = (t >> 2) & 1, nb = t & 3;
            float beta = logf(0.5f / (float)(l + 1) + 1.0f);
            int k = kt * 32 + g * 8 + j, n = nb * 16 + m;
            v = beta * Ws[l * 4096 + k * 64 + n] + ((k == n) ? (1.0f - beta) : 0.0f);
        } else {
            int t = fid - 80;
            int kt = t >> 2, nb = t & 3;
            int k = kt * 32 + g * 8 + j, n = nb * 16 + m;
            v = Wout[k * 64 + n];
        }
        frag[fid * 512 + lane * 8 + j] = __float2half(v);
    }
}

// ---------------- compute kernels ----------------

// h = relu(x @ W0 + b0): MFMA; writes p (dinv-scaled) + h0 rows at RANK positions
__global__ __launch_bounds__(256) void k_layer0(const float* __restrict__ x,
        const __half* __restrict__ frag, const float* __restrict__ b0,
        const float* __restrict__ dinv, const int* __restrict__ rank,
        char* __restrict__ pbuf, char* __restrict__ h0buf) {
    __shared__ __half lds[4][16 * 80];
    int lane = threadIdx.x & 63, wave = threadIdx.x >> 6;
    int gwave = blockIdx.x * 4 + wave, nwaves = gridDim.x * 4;
    int m = lane & 15, g = lane >> 4;
    f16x8 bf[4][4];
    const int4* fb = (const int4*)frag;
#pragma unroll
    for (int kt = 0; kt < 4; kt++)
#pragma unroll
        for (int nb = 0; nb < 4; nb++) {
            int4 r = fb[(kt * 4 + nb) * 64 + lane];
            bf[kt][nb] = *(f16x8*)&r;
        }
    float bb[4];
#pragma unroll
    for (int nb = 0; nb < 4; nb++) bb[nb] = b0[nb * 16 + m];
    __half* L = &lds[wave][0];
    for (int t = gwave; t < NTILE; t += nwaves) {
        int tb = t * 16;
        f32x4 acc[4] = {};
        const float* xrow = x + (size_t)(tb + m) * 128;
#pragma unroll
        for (int kt = 0; kt < 4; kt++) {
            float4 r0 = *(const float4*)(xrow + kt * 32 + g * 8);
            float4 r1 = *(const float4*)(xrow + kt * 32 + g * 8 + 4);
            f16x8 af;
            af[0] = (_Float16)r0.x; af[1] = (_Float16)r0.y;
            af[2] = (_Float16)r0.z; af[3] = (_Float16)r0.w;
            af[4] = (_Float16)r1.x; af[5] = (_Float16)r1.y;
            af[6] = (_Float16)r1.z; af[7] = (_Float16)r1.w;
#pragma unroll
            for (int nb = 0; nb < 4; nb++)
                acc[nb] = __builtin_amdgcn_mfma_f32_16x16x32_f16(af, bf[kt][nb], acc[nb], 0, 0, 0);
        }
#pragma unroll
        for (int nb = 0; nb < 4; nb++)
#pragma unroll
            for (int r = 0; r < 4; r++) {
                int mm = g * 4 + r;
                float y = fmaxf(acc[nb][r] + bb[nb], 0.f);
                L[mm * 80 + nb * 16 + m] = __float2half(y);
            }
        asm volatile("" ::: "memory");
        int n2 = tb + m;
        float dv = dinv[n2];
        int rr = rank[n2];
        int4 lo = *(const int4*)&L[m * 80 + g * 8];
        int4 hi = *(const int4*)&L[m * 80 + 32 + g * 8];
        *(int4*)(h0buf + (size_t)rr * 128 + g * 16) = lo;
        *(int4*)(h0buf + (size_t)rr * 128 + 64 + g * 16) = hi;
        int4 slo, shi;
        const __half2* l2 = (const __half2*)&lo; __half2* s2 = (__half2*)&slo;
        const __half2* h2 = (const __half2*)&hi; __half2* t2 = (__half2*)&shi;
#pragma unroll
        for (int u = 0; u < 4; u++) {
            float2 a = __half22float2(l2[u]); s2[u] = __floats2half2_rn(a.x * dv, a.y * dv);
            float2 b = __half22float2(h2[u]); t2[u] = __floats2half2_rn(b.x * dv, b.y * dv);
        }
        *(int4*)(pbuf + (size_t)rr * 128 + g * 16) = slo;
        *(int4*)(pbuf + (size_t)rr * 128 + 64 + g * 16) = shi;
        asm volatile("" ::: "memory");
    }
}

// FUSED layer (R8 inner loop verbatim), operating in RANK space.
// Tiles have uniform degree; (t0*1563)%3125 swizzle spreads heavy tiles.
__global__ __launch_bounds__(256) void k_flayer(
        const char* __restrict__ pbuf, const char* __restrict__ h0buf,
        const float* __restrict__ dinvp, const __half* __restrict__ frag,
        const int* __restrict__ offsp, const int* __restrict__ csrs2,
        char* __restrict__ pout) {
    __shared__ int    csrl[4][CSRCAP];     // 12 KB
    __shared__ __half aggl[4][16 * 72];    // 9 KB
    __shared__ __half outl[4][16 * 80];    // 10 KB
    int lane = threadIdx.x & 63, wave = threadIdx.x >> 6;
    int t0 = blockIdx.x * 4 + wave;
    if (t0 >= NTILE) return;
    int t = (int)(((long long)t0 * 1563) % NTILE);
    int tb = t * 16;
    int m = lane & 15, g = lane >> 4;

    f16x8 bf[2][4];
    const int4* fb = (const int4*)frag;
#pragma unroll
    for (int kt = 0; kt < 2; kt++)
#pragma unroll
        for (int nb = 0; nb < 4; nb++) {
            int4 r = fb[(kt * 4 + nb) * 64 + lane];
            bf[kt][nb] = *(f16x8*)&r;
        }

    int offv = 0;
    if (lane < 17) offv = offsp[tb + lane];
    int base = __shfl(offv, 0);
    int tot  = __shfl(offv, 16) - base;
    if (tot > CSRCAP) tot = CSRCAP;
    int* cl = csrl[wave];
    for (int i = lane; i < tot; i += 64)
        cl[i] = __builtin_nontemporal_load(csrs2 + base + i);

    int q = lane >> 4, s = (lane >> 3) & 1, fq = lane & 7;
    char* al = (char*)&aggl[wave][0];
#pragma unroll 1
    for (int p = 0; p < 4; p++) {
        int r0 = __shfl(offv, 4 * p + q) - base + s;
        int r1 = __shfl(offv, 4 * p + q + 1) - base;
        __half2 a0 = __floats2half2_rn(0.f, 0.f), a1 = a0, a2 = a0, a3 = a0;
#define GCH(IT) {                                                              \
        int idx = r0 + 2 * (IT);                                               \
        bool v = idx < r1;                                                     \
        int src = cl[v ? idx : 0];                                             \
        src = v ? src : NN;                                                    \
        int4 gld = *(const int4*)(pbuf + (size_t)src * 128 + fq * 16);         \
        a0 = __hadd2(a0, ((const __half2*)&gld)[0]);                           \
        a1 = __hadd2(a1, ((const __half2*)&gld)[1]);                           \
        a2 = __hadd2(a2, ((const __half2*)&gld)[2]);                           \
        a3 = __hadd2(a3, ((const __half2*)&gld)[3]); }
        GCH(0) GCH(1) GCH(2) GCH(3)
        int it = 4;
        while (__any(r0 + 2 * it < r1)) {
            GCH(it) GCH(it + 1)
            it += 2;
        }
#undef GCH
        a0 = __hadd2(a0, __shfl_xor(a0, 8));
        a1 = __hadd2(a1, __shfl_xor(a1, 8));
        a2 = __hadd2(a2, __shfl_xor(a2, 8));
        a3 = __hadd2(a3, __shfl_xor(a3, 8));
        if (s == 0) {
            int4 v;
            v.x = *(int*)&a0; v.y = *(int*)&a1; v.z = *(int*)&a2; v.w = *(int*)&a3;
            *(int4*)(al + (4 * p + q) * 144 + fq * 16) = v;
        }
    }
    asm volatile("" ::: "memory");

    float di = dinvp[tb + m];
    float c9 = 0.9f * di;
    f32x4 acc[4] = {};
#pragma unroll
    for (int kt = 0; kt < 2; kt++) {
        int4 ra = *(const int4*)(al + m * 144 + kt * 64 + g * 16);
        int4 rp = *(const int4*)(pbuf + (size_t)(tb + m) * 128 + kt * 64 + g * 16);
        int4 rh = *(const int4*)(h0buf + (size_t)(tb + m) * 128 + kt * 64 + g * 16);
        f16x8 af;
#pragma unroll
        for (int u = 0; u < 4; u++) {
            float2 fa = __half22float2(((const __half2*)&ra)[u]);
            float2 fp = __half22float2(((const __half2*)&rp)[u]);
            float2 fh = __half22float2(((const __half2*)&rh)[u]);
            af[2 * u]     = (_Float16)(c9 * (fa.x + fp.x) + 0.1f * fh.x);
            af[2 * u + 1] = (_Float16)(c9 * (fa.y + fp.y) + 0.1f * fh.y);
        }
#pragma unroll
        for (int nb = 0; nb < 4; nb++)
            acc[nb] = __builtin_amdgcn_mfma_f32_16x16x32_f16(af, bf[kt][nb], acc[nb], 0, 0, 0);
    }

    __half* L = &outl[wave][0];
    float dvr[4];
#pragma unroll
    for (int r = 0; r < 4; r++) dvr[r] = dinvp[tb + g * 4 + r];
#pragma unroll
    for (int nb = 0; nb < 4; nb++)
#pragma unroll
        for (int r = 0; r < 4; r++) {
            int mm = g * 4 + r;
            float y = fmaxf(acc[nb][r], 0.f) * dvr[r];
            L[mm * 80 + nb * 16 + m] = __float2half(y);
        }
    asm volatile("" ::: "memory");
    int n2 = tb + m;
    int4 lo = *(const int4*)&L[m * 80 + g * 8];
    int4 hi = *(const int4*)&L[m * 80 + 32 + g * 8];
    *(int4*)(pout + (size_t)n2 * 128 + g * 16) = lo;
    *(int4*)(pout + (size_t)n2 * 128 + 64 + g * 16) = hi;
}

// out = (p*rdinv) @ Wout + bout (fp32), un-permuting rows via iperm
__global__ __launch_bounds__(256) void k_out(const char* __restrict__ pbuf,
        const float* __restrict__ rdinvp, const int* __restrict__ iperm,
        const __half* __restrict__ frag,
        const float* __restrict__ bout, float* __restrict__ out) {
    __shared__ float lds[4][16 * 72];
    int lane = threadIdx.x & 63, wave = threadIdx.x >> 6;
    int gwave = blockIdx.x * 4 + wave, nwaves = gridDim.x * 4;
    int m = lane & 15, g = lane >> 4;
    f16x8 bf[2][4];
    const int4* fb = (const int4*)(frag + 80 * 512);
#pragma unroll
    for (int kt = 0; kt < 2; kt++)
#pragma unroll
        for (int nb = 0; nb < 4; nb++) {
            int4 r = fb[(kt * 4 + nb) * 64 + lane];
            bf[kt][nb] = *(f16x8*)&r;
        }
    float bb[4];
#pragma unroll
    for (int nb = 0; nb < 4; nb++) bb[nb] = bout[nb * 16 + m];
    float* L = &lds[wave][0];
    for (int t = gwave; t < NTILE; t += nwaves) {
        int tb = t * 16;
        float rv = rdinvp[tb + m];
        f32x4 acc[4] = {};
#pragma unroll
        for (int kt = 0; kt < 2; kt++) {
            int4 rp = *(const int4*)(pbuf + (size_t)(tb + m) * 128 + kt * 64 + g * 16);
            f16x8 af;
#pragma unroll
            for (int u = 0; u < 4; u++) {
                float2 fp = __half22float2(((const __half2*)&rp)[u]);
                af[2 * u]     = (_Float16)(fp.x * rv);
                af[2 * u + 1] = (_Float16)(fp.y * rv);
            }
#pragma unroll
            for (int nb = 0; nb < 4; nb++)
                acc[nb] = __builtin_amdgcn_mfma_f32_16x16x32_f16(af, bf[kt][nb], acc[nb], 0, 0, 0);
        }
#pragma unroll
        for (int nb = 0; nb < 4; nb++)
#pragma unroll
            for (int r = 0; r < 4; r++)
                L[(g * 4 + r) * 72 + nb * 16 + m] = acc[nb][r] + bb[nb];
        asm volatile("" ::: "memory");
#pragma unroll
        for (int pass = 0; pass < 4; pass++) {
            int nl = pass * 4 + g;
            int onode = iperm[tb + nl];
            float4 v = *(const float4*)&L[nl * 72 + m * 4];
            *(float4*)(out + (size_t)onode * 64 + m * 4) = v;
        }
        asm volatile("" ::: "memory");
    }
}

// ---------------- launch ----------------

static inline size_t al256(size_t x) { return (x + 255) & ~(size_t)255; }

extern "C" void kernel_launch(void* const* d_in, const int* in_sizes, int n_in,
                              void* d_out, int out_size, void* d_ws, size_t ws_size,
                              hipStream_t stream) {
    const float* x    = (const float*)d_in[0];
    const int*   ei   = (const int*)d_in[1];
    const float* W0   = (const float*)d_in[2];
    const float* b0   = (const float*)d_in[3];
    const float* Ws   = (const float*)d_in[4];
    const float* Wout = (const float*)d_in[5];
    const float* bout = (const float*)d_in[6];
    float* out = (float*)d_out;

    char* w = (char*)d_ws;
    size_t off = 0;
    const size_t ROWS = (size_t)(NN + 1) * 128;
    int* gh      = (int*)(w + off); off = al256(off + (size_t)256 * 256 * 4);
    int* bbase   = (int*)(w + off); off = al256(off + (size_t)257 * 4);
    int2* part   = (int2*)(w + off); off = al256(off + (size_t)NE * 8);
    int* csrs    = (int*)(w + off); off = al256(off + ((size_t)NE + 256) * 4);
    int* csrs2   = (int*)(w + off); off = al256(off + ((size_t)NE + 256) * 4);
    int* offs    = (int*)(w + off); off = al256(off + ((size_t)NN + 1) * 4);
    int* offsp   = (int*)(w + off); off = al256(off + ((size_t)NN + 1) * 4);
    int* rank    = (int*)(w + off); off = al256(off + (size_t)NN * 4);
    int* iperm   = (int*)(w + off); off = al256(off + (size_t)NN * 4);
    float* dinv  = (float*)(w + off); off = al256(off + (size_t)NN * 4);
    float* rdinv = (float*)(w + off); off = al256(off + (size_t)NN * 4);
    float* dinvp = (float*)(w + off); off = al256(off + (size_t)NN * 4);
    float* rdinvp= (float*)(w + off); off = al256(off + (size_t)NN * 4);
    int* dh      = (int*)(w + off); off = al256(off + (size_t)64 * 4);
    int* dbase   = (int*)(w + off); off = al256(off + (size_t)64 * 4);
    int* ebase   = (int*)(w + off); off = al256(off + (size_t)64 * 4);
    int* binpos  = (int*)(w + off); off = al256(off + (size_t)64 * 4);
    __half* frag = (__half*)(w + off); off = al256(off + (size_t)88 * 512 * 2);
    char* pA     = (char*)(w + off); off = al256(off + ROWS);
    char* pB     = (char*)(w + off); off = al256(off + ROWS);
    char* h0b    = (char*)(w + off); off = al256(off + (size_t)NN * 128);

    hipMemsetAsync(dh, 0, 64 * 4, stream);

    k_hist<<<256, 256, 0, stream>>>(ei, gh);
    k_scanhist<<<1, 256, 0, stream>>>(gh, bbase);
    k_part<<<256, 256, 0, stream>>>(ei, gh, part);
    k_bsort<<<NBUCKB, 256, 0, stream>>>(part, bbase, csrs, offs, dinv, rdinv);
    k_deghist<<<NBUCKB, 256, 0, stream>>>(offs, dh);
    k_degscan<<<1, 64, 0, stream>>>(dh, dbase, ebase, binpos);
    k_rank<<<NBUCKB, 256, 0, stream>>>(offs, binpos, dbase, ebase, dinv, rdinv,
                                       rank, iperm, offsp, dinvp, rdinvp);
    k_remap<<<NBUCKB, 256, 0, stream>>>(offs, rank, offsp, csrs, csrs2);
    k_zrow<<<1, 64, 0, stream>>>((__half2*)pA, (__half2*)pB);
    k_makefrag<<<88, 64, 0, stream>>>(W0, Ws, Wout, frag);

    k_layer0<<<784, 256, 0, stream>>>(x, frag, b0, dinv, rank, pA, h0b);

    const char* cur = pA;
    char* nxt = pB;
    for (int l = 0; l < NLAYERS; l++) {
        k_flayer<<<(NTILE + 3) / 4, 256, 0, stream>>>(cur, h0b, dinvp,
                frag + (16 + l * 8) * 512, offsp, csrs2, nxt);
        char* t2 = nxt;
        nxt = (char*)cur;
        cur = t2;
    }
    k_out<<<784, 256, 0, stream>>>(cur, rdinvp, iperm, frag, bout, out);
}

// Round 13
// 215.691 us; speedup vs baseline: 1.9537x; 1.9537x over previous
//
#include <hip/hip_runtime.h>
#include <hip/hip_fp16.h>
#include <math.h>

#define NN 50000
#define NE 800000
#define NLAYERS 8
#define NTILE (NN / 16)                     // 3125 16-node tiles
#define EPB (NE / 256)                      // 3125 edges per hist/part block
#define NBUCKB ((NN + 255) / 256)           // 196 buckets in use
#define BCAP 5120                           // max edges per bucket
#define CSRCAP 512                          // max edges per 16-node tile

typedef _Float16 f16x8 __attribute__((ext_vector_type(8)));
typedef float f32x4 __attribute__((ext_vector_type(4)));

// ---------------- CSR build: 4-pass radix partition (R8 verbatim) ----------------

__global__ __launch_bounds__(256) void k_hist(const int* __restrict__ ei,
                                              int* __restrict__ gh) {
    __shared__ int h[256];
    h[threadIdx.x] = 0;
    __syncthreads();
    int base = blockIdx.x * EPB;
    for (int i = threadIdx.x; i < EPB; i += 256) {
        int d = __builtin_nontemporal_load(ei + NE + base + i);
        atomicAdd(&h[d >> 8], 1);
    }
    __syncthreads();
    gh[blockIdx.x * 256 + threadIdx.x] = h[threadIdx.x];
}

__global__ void k_scanhist(int* __restrict__ gh, int* __restrict__ bbase) {
    __shared__ int tot[256];
    int t = threadIdx.x;
    int run = 0;
    for (int blk = 0; blk < 256; blk++) {
        int v = gh[blk * 256 + t];
        gh[blk * 256 + t] = run;
        run += v;
    }
    tot[t] = run;
    __syncthreads();
    for (int off = 1; off < 256; off <<= 1) {
        int u = (t >= off) ? tot[t - off] : 0;
        __syncthreads();
        tot[t] += u;
        __syncthreads();
    }
    int ebase = tot[t] - run;
    for (int blk = 0; blk < 256; blk++) gh[blk * 256 + t] += ebase;
    bbase[t] = ebase;
    if (t == 255) bbase[256] = NE;
}

__global__ __launch_bounds__(256) void k_part(const int* __restrict__ ei,
                                              const int* __restrict__ gh,
                                              int2* __restrict__ part) {
    __shared__ int lcnt[256];
    int t = threadIdx.x;
    lcnt[t] = gh[blockIdx.x * 256 + t];
    __syncthreads();
    int base = blockIdx.x * EPB;
    for (int i = t; i < EPB; i += 256) {
        int s = __builtin_nontemporal_load(ei + base + i);
        int d = __builtin_nontemporal_load(ei + NE + base + i);
        int pos = atomicAdd(&lcnt[d >> 8], 1);
        int2 e; e.x = s; e.y = d;
        part[pos] = e;
    }
}

__global__ __launch_bounds__(256) void k_bsort(const int2* __restrict__ part,
                                               const int* __restrict__ bbase,
                                               int* __restrict__ csrs,
                                               int* __restrict__ offs,
                                               float* __restrict__ dinv,
                                               float* __restrict__ rdinv) {
    __shared__ int ssrc[BCAP];
    __shared__ unsigned char sdlo[BCAP];
    __shared__ int dcnt[256], dpos[256], scan[256];
    int b = blockIdx.x, t = threadIdx.x;
    int base0 = bbase[b], base1 = bbase[b + 1];
    int n = base1 - base0;
    if (n > BCAP) n = BCAP;
    dcnt[t] = 0;
    __syncthreads();
    for (int i = t; i < n; i += 256) {
        int2 e = part[base0 + i];
        ssrc[i] = e.x;
        int dlo = e.y & 255;
        sdlo[i] = (unsigned char)dlo;
        atomicAdd(&dcnt[dlo], 1);
    }
    __syncthreads();
    int cnt = dcnt[t];
    scan[t] = cnt;
    __syncthreads();
    for (int off = 1; off < 256; off <<= 1) {
        int u = (t >= off) ? scan[t - off] : 0;
        __syncthreads();
        scan[t] += u;
        __syncthreads();
    }
    int ebase = scan[t] - cnt;
    dpos[t] = ebase;
    __syncthreads();
    for (int i = t; i < n; i += 256) {
        int d = sdlo[i];
        int r = atomicAdd(&dpos[d], 1);
        csrs[base0 + r] = ssrc[i];
    }
    int gdst = b * 256 + t;
    if (gdst < NN) {
        offs[gdst] = base0 + ebase;
        float dd = (float)(cnt + 1);
        dinv[gdst] = rsqrtf(dd);
        rdinv[gdst] = sqrtf(dd);
    } else if (gdst == NN) {
        offs[NN] = NE;
    }
}

// ---------------- other setup ----------------
// MERGED row layout: row[node] = 128B = 64 halves (feats 0-63). One cache line.

// zero row NN of pA and pB (gather target for clamped slots)
__global__ void k_zrow(__half2* a, __half2* b) {
    int t = threadIdx.x;
    __half2 z = __floats2half2_rn(0.f, 0.f);
    if (t < 32) a[NN * 32 + t] = z;
    else b[NN * 32 + (t & 31)] = z;
}

// frag[fid][lane][j] = B[k = kt*32 + (lane>>4)*8 + j][n = nb*16 + (lane&15)]
// fid 0..15: W0; 16..79: M_l = (1-b)I + b*Ws[l]; 80..87: Wout.
__global__ void k_makefrag(const float* __restrict__ W0, const float* __restrict__ Ws,
                           const float* __restrict__ Wout, __half* __restrict__ frag) {
    int fid = blockIdx.x;
    int lane = threadIdx.x;
    int m = lane & 15, g = lane >> 4;
#pragma unroll
    for (int j = 0; j < 8; j++) {
        float v;
        if (fid < 16) {
            int kt = fid >> 2, nb = fid & 3;
            int k = kt * 32 + g * 8 + j, n = nb * 16 + m;
            v = W0[k * 64 + n];
        } else if (fid < 80) {
            int t = fid - 16;
            int l = t >> 3, kt = (t >> 2) & 1, nb = t & 3;
            float beta = logf(0.5f / (float)(l + 1) + 1.0f);
            int k = kt * 32 + g * 8 + j, n = nb * 16 + m;
            v = beta * Ws[l * 4096 + k * 64 + n] + ((k == n) ? (1.0f - beta) : 0.0f);
        } else {
            int t = fid - 80;
            int kt = t >> 2, nb = t & 3;
            int k = kt * 32 + g * 8 + j, n = nb * 16 + m;
            v = Wout[k * 64 + n];
        }
        frag[fid * 512 + lane * 8 + j] = __float2half(v);
    }
}

// ---------------- compute kernels ----------------

// h = relu(x @ W0 + b0): MFMA, writes merged p rows (dinv-scaled) + h0 rows
__global__ __launch_bounds__(256) void k_layer0(const float* __restrict__ x,
        const __half* __restrict__ frag, const float* __restrict__ b0,
        const float* __restrict__ dinv,
        char* __restrict__ pbuf, char* __restrict__ h0buf) {
    __shared__ __half lds[4][16 * 80];
    int lane = threadIdx.x & 63, wave = threadIdx.x >> 6;
    int gwave = blockIdx.x * 4 + wave, nwaves = gridDim.x * 4;
    int m = lane & 15, g = lane >> 4;
    f16x8 bf[4][4];
    const int4* fb = (const int4*)frag;
#pragma unroll
    for (int kt = 0; kt < 4; kt++)
#pragma unroll
        for (int nb = 0; nb < 4; nb++) {
            int4 r = fb[(kt * 4 + nb) * 64 + lane];
            bf[kt][nb] = *(f16x8*)&r;
        }
    float bb[4];
#pragma unroll
    for (int nb = 0; nb < 4; nb++) bb[nb] = b0[nb * 16 + m];
    __half* L = &lds[wave][0];
    for (int t = gwave; t < NTILE; t += nwaves) {
        int tb = t * 16;
        f32x4 acc[4] = {};
        const float* xrow = x + (size_t)(tb + m) * 128;
#pragma unroll
        for (int kt = 0; kt < 4; kt++) {
            float4 r0 = *(const float4*)(xrow + kt * 32 + g * 8);
            float4 r1 = *(const float4*)(xrow + kt * 32 + g * 8 + 4);
            f16x8 af;
            af[0] = (_Float16)r0.x; af[1] = (_Float16)r0.y;
            af[2] = (_Float16)r0.z; af[3] = (_Float16)r0.w;
            af[4] = (_Float16)r1.x; af[5] = (_Float16)r1.y;
            af[6] = (_Float16)r1.z; af[7] = (_Float16)r1.w;
#pragma unroll
            for (int nb = 0; nb < 4; nb++)
                acc[nb] = __builtin_amdgcn_mfma_f32_16x16x32_f16(af, bf[kt][nb], acc[nb], 0, 0, 0);
        }
#pragma unroll
        for (int nb = 0; nb < 4; nb++)
#pragma unroll
            for (int r = 0; r < 4; r++) {
                int mm = g * 4 + r;
                float y = fmaxf(acc[nb][r] + bb[nb], 0.f);
                L[mm * 80 + nb * 16 + m] = __float2half(y);
            }
        asm volatile("" ::: "memory");
        int n2 = tb + m;
        float dv = dinv[n2];
        int4 lo = *(const int4*)&L[m * 80 + g * 8];
        int4 hi = *(const int4*)&L[m * 80 + 32 + g * 8];
        *(int4*)(h0buf + (size_t)n2 * 128 + g * 16) = lo;
        *(int4*)(h0buf + (size_t)n2 * 128 + 64 + g * 16) = hi;
        int4 slo, shi;
        const __half2* l2 = (const __half2*)&lo; __half2* s2 = (__half2*)&slo;
        const __half2* h2 = (const __half2*)&hi; __half2* t2 = (__half2*)&shi;
#pragma unroll
        for (int u = 0; u < 4; u++) {
            float2 a = __half22float2(l2[u]); s2[u] = __floats2half2_rn(a.x * dv, a.y * dv);
            float2 b = __half22float2(h2[u]); t2[u] = __floats2half2_rn(b.x * dv, b.y * dv);
        }
        *(int4*)(pbuf + (size_t)n2 * 128 + g * 16) = slo;
        *(int4*)(pbuf + (size_t)n2 * 128 + 64 + g * 16) = shi;
        asm volatile("" ::: "memory");
    }
}

// FUSED layer (R8 structure; ONLY change: while-loop body widened 2->4 GCH,
// doubling steady-state loads-in-flight per wave — tests latency- vs BW-bound).
__global__ __launch_bounds__(256) void k_flayer(
        const char* __restrict__ pbuf, const char* __restrict__ h0buf,
        const float* __restrict__ dinv, const __half* __restrict__ frag,
        const int* __restrict__ offs, const int* __restrict__ csrs,
        char* __restrict__ pout) {
    __shared__ int    csrl[4][CSRCAP];     // 2048B/wave
    __shared__ __half aggl[4][16 * 72];    // 144B row stride
    __shared__ __half outl[4][16 * 80];
    int lane = threadIdx.x & 63, wave = threadIdx.x >> 6;
    int t = blockIdx.x * 4 + wave;
    if (t >= NTILE) return;
    int tb = t * 16;
    int m = lane & 15, g = lane >> 4;

    f16x8 bf[2][4];
    const int4* fb = (const int4*)frag;
#pragma unroll
    for (int kt = 0; kt < 2; kt++)
#pragma unroll
        for (int nb = 0; nb < 4; nb++) {
            int4 r = fb[(kt * 4 + nb) * 64 + lane];
            bf[kt][nb] = *(f16x8*)&r;
        }

    int offv = 0;
    if (lane < 17) offv = offs[tb + lane];
    int base = __shfl(offv, 0);
    int tot  = __shfl(offv, 16) - base;
    if (tot > CSRCAP) tot = CSRCAP;
    int* cl = csrl[wave];
    for (int i = lane; i < tot; i += 64)
        cl[i] = __builtin_nontemporal_load(csrs + base + i);

    int q = lane >> 4, s = (lane >> 3) & 1, fq = lane & 7;
    char* al = (char*)&aggl[wave][0];
#pragma unroll 1
    for (int p = 0; p < 4; p++) {
        int r0 = __shfl(offv, 4 * p + q) - base + s;
        int r1 = __shfl(offv, 4 * p + q + 1) - base;
        __half2 a0 = __floats2half2_rn(0.f, 0.f), a1 = a0, a2 = a0, a3 = a0;
#define GCH(IT) {                                                              \
        int idx = r0 + 2 * (IT);                                               \
        bool v = idx < r1;                                                     \
        int src = cl[v ? idx : 0];                                             \
        src = v ? src : NN;                                                    \
        int4 gld = *(const int4*)(pbuf + (size_t)src * 128 + fq * 16);         \
        a0 = __hadd2(a0, ((const __half2*)&gld)[0]);                           \
        a1 = __hadd2(a1, ((const __half2*)&gld)[1]);                           \
        a2 = __hadd2(a2, ((const __half2*)&gld)[2]);                           \
        a3 = __hadd2(a3, ((const __half2*)&gld)[3]); }
        GCH(0) GCH(1) GCH(2) GCH(3)
        int it = 4;
        while (__any(r0 + 2 * it < r1)) {
            GCH(it) GCH(it + 1) GCH(it + 2) GCH(it + 3)
            it += 4;
        }
#undef GCH
        a0 = __hadd2(a0, __shfl_xor(a0, 8));
        a1 = __hadd2(a1, __shfl_xor(a1, 8));
        a2 = __hadd2(a2, __shfl_xor(a2, 8));
        a3 = __hadd2(a3, __shfl_xor(a3, 8));
        if (s == 0) {
            int4 v;
            v.x = *(int*)&a0; v.y = *(int*)&a1; v.z = *(int*)&a2; v.w = *(int*)&a3;
            *(int4*)(al + (4 * p + q) * 144 + fq * 16) = v;
        }
    }
    asm volatile("" ::: "memory");

    float di = dinv[tb + m];
    float c9 = 0.9f * di;
    f32x4 acc[4] = {};
#pragma unroll
    for (int kt = 0; kt < 2; kt++) {
        int4 ra = *(const int4*)(al + m * 144 + kt * 64 + g * 16);
        int4 rp = *(const int4*)(pbuf + (size_t)(tb + m) * 128 + kt * 64 + g * 16);
        int4 rh = *(const int4*)(h0buf + (size_t)(tb + m) * 128 + kt * 64 + g * 16);
        f16x8 af;
#pragma unroll
        for (int u = 0; u < 4; u++) {
            float2 fa = __half22float2(((const __half2*)&ra)[u]);
            float2 fp = __half22float2(((const __half2*)&rp)[u]);
            float2 fh = __half22float2(((const __half2*)&rh)[u]);
            af[2 * u]     = (_Float16)(c9 * (fa.x + fp.x) + 0.1f * fh.x);
            af[2 * u + 1] = (_Float16)(c9 * (fa.y + fp.y) + 0.1f * fh.y);
        }
#pragma unroll
        for (int nb = 0; nb < 4; nb++)
            acc[nb] = __builtin_amdgcn_mfma_f32_16x16x32_f16(af, bf[kt][nb], acc[nb], 0, 0, 0);
    }

    __half* L = &outl[wave][0];
    float dvr[4];
#pragma unroll
    for (int r = 0; r < 4; r++) dvr[r] = dinv[tb + g * 4 + r];
#pragma unroll
    for (int nb = 0; nb < 4; nb++)
#pragma unroll
        for (int r = 0; r < 4; r++) {
            int mm = g * 4 + r;
            float y = fmaxf(acc[nb][r], 0.f) * dvr[r];
            L[mm * 80 + nb * 16 + m] = __float2half(y);
        }
    asm volatile("" ::: "memory");
    int n2 = tb + m;
    int4 lo = *(const int4*)&L[m * 80 + g * 8];
    int4 hi = *(const int4*)&L[m * 80 + 32 + g * 8];
    *(int4*)(pout + (size_t)n2 * 128 + g * 16) = lo;
    *(int4*)(pout + (size_t)n2 * 128 + 64 + g * 16) = hi;
}

// out = (p*rdinv) @ Wout + bout   (fp32 out)
__global__ __launch_bounds__(256) void k_out(const char* __restrict__ pbuf,
        const float* __restrict__ rdinv, const __half* __restrict__ frag,
        const float* __restrict__ bout, float* __restrict__ out) {
    __shared__ float lds[4][16 * 72];
    int lane = threadIdx.x & 63, wave = threadIdx.x >> 6;
    int gwave = blockIdx.x * 4 + wave, nwaves = gridDim.x * 4;
    int m = lane & 15, g = lane >> 4;
    f16x8 bf[2][4];
    const int4* fb = (const int4*)(frag + 80 * 512);
#pragma unroll
    for (int kt = 0; kt < 2; kt++)
#pragma unroll
        for (int nb = 0; nb < 4; nb++) {
            int4 r = fb[(kt * 4 + nb) * 64 + lane];
            bf[kt][nb] = *(f16x8*)&r;
        }
    float bb[4];
#pragma unroll
    for (int nb = 0; nb < 4; nb++) bb[nb] = bout[nb * 16 + m];
    float* L = &lds[wave][0];
    for (int t = gwave; t < NTILE; t += nwaves) {
        int tb = t * 16;
        float rv = rdinv[tb + m];
        f32x4 acc[4] = {};
#pragma unroll
        for (int kt = 0; kt < 2; kt++) {
            int4 rp = *(const int4*)(pbuf + (size_t)(tb + m) * 128 + kt * 64 + g * 16);
            f16x8 af;
#pragma unroll
            for (int u = 0; u < 4; u++) {
                float2 fp = __half22float2(((const __half2*)&rp)[u]);
                af[2 * u]     = (_Float16)(fp.x * rv);
                af[2 * u + 1] = (_Float16)(fp.y * rv);
            }
#pragma unroll
            for (int nb = 0; nb < 4; nb++)
                acc[nb] = __builtin_amdgcn_mfma_f32_16x16x32_f16(af, bf[kt][nb], acc[nb], 0, 0, 0);
        }
#pragma unroll
        for (int nb = 0; nb < 4; nb++)
#pragma unroll
            for (int r = 0; r < 4; r++)
                L[(g * 4 + r) * 72 + nb * 16 + m] = acc[nb][r] + bb[nb];
        asm volatile("" ::: "memory");
#pragma unroll
        for (int pass = 0; pass < 4; pass++) {
            int nl = pass * 4 + g;
            float4 v = *(const float4*)&L[nl * 72 + m * 4];
            *(float4*)(out + (size_t)(tb + nl) * 64 + m * 4) = v;
        }
        asm volatile("" ::: "memory");
    }
}

// ---------------- launch ----------------

static inline size_t al256(size_t x) { return (x + 255) & ~(size_t)255; }

extern "C" void kernel_launch(void* const* d_in, const int* in_sizes, int n_in,
                              void* d_out, int out_size, void* d_ws, size_t ws_size,
                              hipStream_t stream) {
    const float* x    = (const float*)d_in[0];
    const int*   ei   = (const int*)d_in[1];
    const float* W0   = (const float*)d_in[2];
    const float* b0   = (const float*)d_in[3];
    const float* Ws   = (const float*)d_in[4];
    const float* Wout = (const float*)d_in[5];
    const float* bout = (const float*)d_in[6];
    float* out = (float*)d_out;

    char* w = (char*)d_ws;
    size_t off = 0;
    const size_t ROWS = (size_t)(NN + 1) * 128;
    int* gh      = (int*)(w + off); off = al256(off + (size_t)256 * 256 * 4);
    int* bbase   = (int*)(w + off); off = al256(off + (size_t)257 * 4);
    int2* part   = (int2*)(w + off); off = al256(off + (size_t)NE * 8);
    int* csrs    = (int*)(w + off); off = al256(off + ((size_t)NE + 256) * 4);
    int* offs    = (int*)(w + off); off = al256(off + ((size_t)NN + 1) * 4);
    float* dinv  = (float*)(w + off); off = al256(off + (size_t)NN * 4);
    float* rdinv = (float*)(w + off); off = al256(off + (size_t)NN * 4);
    __half* frag = (__half*)(w + off); off = al256(off + (size_t)88 * 512 * 2);
    char* pA     = (char*)(w + off); off = al256(off + ROWS);
    char* pB     = (char*)(w + off); off = al256(off + ROWS);
    char* h0b    = (char*)(w + off); off = al256(off + (size_t)NN * 128);

    k_hist<<<256, 256, 0, stream>>>(ei, gh);
    k_scanhist<<<1, 256, 0, stream>>>(gh, bbase);
    k_part<<<256, 256, 0, stream>>>(ei, gh, part);
    k_bsort<<<NBUCKB, 256, 0, stream>>>(part, bbase, csrs, offs, dinv, rdinv);
    k_zrow<<<1, 64, 0, stream>>>((__half2*)pA, (__half2*)pB);
    k_makefrag<<<88, 64, 0, stream>>>(W0, Ws, Wout, frag);

    k_layer0<<<784, 256, 0, stream>>>(x, frag, b0, dinv, pA, h0b);

    const char* cur = pA;
    char* nxt = pB;
    for (int l = 0; l < NLAYERS; l++) {
        k_flayer<<<(NTILE + 3) / 4, 256, 0, stream>>>(cur, h0b, dinv,
                frag + (16 + l * 8) * 512, offs, csrs, nxt);
        char* t2 = nxt;
        nxt = (char*)cur;
        cur = t2;
    }
    k_out<<<784, 256, 0, stream>>>(cur, rdinv, frag, bout, out);
}